// Round 7
// baseline (353.598 us; speedup 1.0000x reference)
//
#include <hip/hip_runtime.h>
#include <hip/hip_fp16.h>
#include <stdint.h>

#define NN 100000
#define D 128
#define W0 128                         // nodes per bucket (power of 2)
#define NB ((NN + W0 - 1) / W0)        // 782 buckets
#define C1 4096                        // edges per chunk (391 partition blocks)
#define CAP 4096                       // per-bucket record capacity (middle tier)
#define NCAP 64                        // per-node slot capacity (fast tier; Poisson(16) max ~42)
#define OVF_CAP 65536                  // global overflow entries (degenerate inputs)

typedef _Float16 f16x8 __attribute__((ext_vector_type(8)));
typedef float f32x4 __attribute__((ext_vector_type(4)));

// ---- workspace layout (bytes) ----
static const size_t O_FLAG   = 0;                      // detect flag (fallback)
static const size_t O_BCNT   = 256;                    // NB ints (fallback)
static const size_t O_BSTART = O_BCNT + 4096;          // NB+1 ints (fallback)
static const size_t O_BCUR   = O_BSTART + 4096;        // NB ints + ovf counter @ +3200 (middle)
static const size_t O_WTL    = O_BCUR + 4096;          // 64KB: packed Bp / WtL (fallback)
static const size_t O_WTR    = O_WTL + (size_t)D * D * 4;
static const size_t O_OFFS   = O_WTR + (size_t)D * D * 4;    // (NN+64) ints: ncur (fast) / offs (fallback)
static const size_t O_DEG    = O_OFFS + (size_t)(NN + 64) * 4;
static const size_t O_RECS   = O_DEG + (size_t)NN * 4;       // recs (middle) / nrec (fast)
// fast tier:   O_NREC = O_RECS (NN*NCAP ints), O_OVF_N after, O_XH_N after
// middle tier: recs NB*CAP, O_OVF after, O_XH after

__device__ __forceinline__ int edge_at(const int* ei, long long pos, int is64) {
    return is64 ? ei[2 * pos] : ei[pos];
}

__device__ __forceinline__ void detect_is64(const int* __restrict__ ei, long long E,
                                            int t, int* s_is64) {
    if (t < 64) {
        int bad = 0;
        if (t < E)      bad |= (ei[2 * t + 1] != 0);
        if (t + 64 < E) bad |= (ei[2 * (t + 64) + 1] != 0);
        unsigned long long m = __ballot(bad);
        if (t == 0) *s_is64 = (m == 0ull) ? 1 : 0;
    }
}

// ================= FAST TIER: per-node slots, no sort =================
// K1: detect + weight-pack + fp16 conv + single-pass per-node append.
__global__ __launch_bounds__(256) void k_build2(
        const float* __restrict__ x, const int* __restrict__ ei,
        const float* __restrict__ Wl, const float* __restrict__ Wr,
        __half* __restrict__ xh, __half* __restrict__ Bp,
        int* __restrict__ ncur, int* __restrict__ ovfc,
        unsigned long long* __restrict__ ovf,
        int* __restrict__ nrec, long long E)
{
    __shared__ int s_is64;
    int t = threadIdx.x, b = blockIdx.x;
    detect_is64(ei, E, t, &s_is64);
    __syncthreads();
    int is64 = s_is64;

    // weight pack into MFMA B-fragment order (blocks 0..127)
    int idx = b * 256 + t;
    if (idx < 32768) {
        int j  = idx & 7;
        int l  = (idx >> 3) & 63;
        int tt = (idx >> 9) & 7;
        int s  = idx >> 12;
        int col = tt * 16 + (l & 15);
        int k   = s * 32 + (l >> 4) * 8 + j;
        float v = (k < 128) ? Wl[col * 128 + k] : Wr[col * 128 + (k - 128)];
        Bp[idx] = __float2half_rn(v);
    }
    // fp16 conversion of x (grid-stride)
    const long long n4 = (long long)NN * D / 4;
    for (long long i = (long long)b * 256 + t; i < n4; i += (long long)gridDim.x * 256) {
        float4 v = ((const float4*)x)[i];
        ((__half2*)xh)[2 * i]     = __floats2half2_rn(v.x, v.y);
        ((__half2*)xh)[2 * i + 1] = __floats2half2_rn(v.z, v.w);
    }
    // single-pass append into per-node slots
    long long base = (long long)b * C1;
    for (int j = t; j < C1; j += 256) {
        long long e = base + j;
        if (e < E) {
            int s = edge_at(ei, e, is64);
            int d = edge_at(ei, E + e, is64);
            int pos = atomicAdd(&ncur[d], 1);
            if (pos < NCAP) nrec[(long long)d * NCAP + pos] = s;
            else {
                int op = atomicAdd(ovfc, 1);
                if (op < OVF_CAP) ovf[op] = ((unsigned long long)d << 32) | (unsigned)s;
            }
        }
    }
}

// K2: gather (R1-style, high occupancy) + fused MFMA GEMM + L2 norm.
// 256 thr = 4 waves; wave w owns nodes blk*64 + w*16 .. +15 = its A-tile rows.
// aw is wave-private -> NO barriers. LDS 16.9 KB -> 8 blocks/CU.
__global__ __launch_bounds__(256) void k_aggemm(
        const int* __restrict__ nrec, const int* __restrict__ ncur,
        const int* __restrict__ ovfc, const unsigned long long* __restrict__ ovf,
        const __half* __restrict__ xh, const __half* __restrict__ Bp,
        const float* __restrict__ bl, float* __restrict__ out, int N)
{
    __shared__ __half aw[4][16][132];   // pad 132: stride 66 words -> 2-way banks (free)
    int t = threadIdx.x, b = blockIdx.x;
    int lane = t & 63;
    int wid  = t >> 6;
    int oc = *ovfc;
    if (oc > OVF_CAP) oc = OVF_CAP;
    const __half2* x2 = (const __half2*)xh;

    // ---- gather: 16 nodes per wave, 8-deep MLP, results -> aw ----
    for (int i = 0; i < 16; ++i) {
        int node = b * 64 + wid * 16 + i;
        if (node >= N) break;
        int deg = ncur[node];
        int cnt = (deg < NCAP) ? deg : NCAP;
        const int* sp = nrec + (long long)node * NCAP;
        float ax = 0.f, ay = 0.f;
        int e = 0;
        for (; e + 8 <= cnt; e += 8) {
            int ss[8];
#pragma unroll
            for (int u = 0; u < 8; ++u) ss[u] = sp[e + u];
            __half2 h[8];
#pragma unroll
            for (int u = 0; u < 8; ++u) h[u] = x2[(long long)ss[u] * 64 + lane];
#pragma unroll
            for (int u = 0; u < 8; ++u) {
                float2 v = __half22float2(h[u]);
                ax += v.x; ay += v.y;
            }
        }
        for (; e + 2 <= cnt; e += 2) {
            int sa = sp[e], sb = sp[e + 1];
            float2 v0 = __half22float2(x2[(long long)sa * 64 + lane]);
            float2 v1 = __half22float2(x2[(long long)sb * 64 + lane]);
            ax += v0.x + v1.x;
            ay += v0.y + v1.y;
        }
        if (e < cnt) {
            float2 v = __half22float2(x2[(long long)sp[e] * 64 + lane]);
            ax += v.x; ay += v.y;
        }
        if (deg > NCAP && oc > 0) {         // overflow slow path (normally never)
            for (int k = 0; k < oc; ++k) {
                unsigned long long v = ovf[k];
                if ((int)(v >> 32) == node) {
                    float2 w = __half22float2(x2[(long long)(unsigned)v * 64 + lane]);
                    ax += w.x; ay += w.y;
                }
            }
        }
        float inv = 1.0f / fmaxf((float)deg, 1.0f);
        *(__half2*)&aw[wid][i][2 * lane] = __floats2half2_rn(ax * inv, ay * inv);
    }
    // aw rows written by this wave only -> proceed straight to MFMA.

    // ---- fused GEMM: out[16x128] = [agg|x](16x256) @ Bp + bias, then L2 norm ----
    f32x4 acc[8];
#pragma unroll
    for (int c = 0; c < 8; ++c) acc[c] = (f32x4){0.f, 0.f, 0.f, 0.f};

    int rn = b * 64 + wid * 16 + (lane & 15);
    long long rx = (rn < N) ? rn : (N - 1);
    int koff = (lane >> 4) * 8;
#pragma unroll
    for (int s = 0; s < 8; ++s) {
        f16x8 a;
        if (s < 4) a = *(const f16x8*)&aw[wid][lane & 15][s * 32 + koff];
        else       a = *(const f16x8*)(xh + rx * 128 + (s & 3) * 32 + koff);
        const __half* bp = Bp + ((s * 8) * 64 + lane) * 8;
#pragma unroll
        for (int tt = 0; tt < 8; ++tt) {
            f16x8 bf = *(const f16x8*)(bp + tt * 512);
            acc[tt] = __builtin_amdgcn_mfma_f32_16x16x32_f16(a, bf, acc[tt], 0, 0, 0);
        }
    }

    float bias[8];
#pragma unroll
    for (int tt = 0; tt < 8; ++tt) bias[tt] = bl[tt * 16 + (lane & 15)];

#pragma unroll
    for (int r = 0; r < 4; ++r) {
        int node = b * 64 + wid * 16 + (lane >> 4) * 4 + r;
        float v[8];
        float ss = 0.f;
#pragma unroll
        for (int tt = 0; tt < 8; ++tt) {
            v[tt] = acc[tt][r] + bias[tt];
            ss = fmaf(v[tt], v[tt], ss);
        }
        ss += __shfl_xor(ss, 1, 64);
        ss += __shfl_xor(ss, 2, 64);
        ss += __shfl_xor(ss, 4, 64);
        ss += __shfl_xor(ss, 8, 64);
        float scale = 1.0f / fmaxf(sqrtf(ss), 1e-12f);
        if (node < N) {
            float* op = out + (long long)node * D + (lane & 15);
#pragma unroll
            for (int tt = 0; tt < 8; ++tt)
                op[tt * 16] = v[tt] * scale;
        }
    }
}

// ================= MIDDLE TIER (R6-proven: bucket slots + in-LDS sort) =================
__global__ __launch_bounds__(256) void k_build(
        const float* __restrict__ x, const int* __restrict__ ei,
        const float* __restrict__ Wl, const float* __restrict__ Wr,
        __half* __restrict__ xh, __half* __restrict__ Bp,
        int* __restrict__ bcur, int* __restrict__ ovf_cnt,
        unsigned long long* __restrict__ ovf,
        unsigned int* __restrict__ recs, long long E)
{
    __shared__ int cnt[NB];
    __shared__ int rbase[NB];
    __shared__ int s_is64;
    int t = threadIdx.x, b = blockIdx.x;
    detect_is64(ei, E, t, &s_is64);
    for (int i = t; i < NB; i += 256) cnt[i] = 0;
    __syncthreads();
    int is64 = s_is64;

    int idx = b * 256 + t;
    if (idx < 32768) {
        int j  = idx & 7;
        int l  = (idx >> 3) & 63;
        int tt = (idx >> 9) & 7;
        int s  = idx >> 12;
        int col = tt * 16 + (l & 15);
        int k   = s * 32 + (l >> 4) * 8 + j;
        float v = (k < 128) ? Wl[col * 128 + k] : Wr[col * 128 + (k - 128)];
        Bp[idx] = __float2half_rn(v);
    }
    const long long n4 = (long long)NN * D / 4;
    for (long long i = (long long)b * 256 + t; i < n4; i += (long long)gridDim.x * 256) {
        float4 v = ((const float4*)x)[i];
        ((__half2*)xh)[2 * i]     = __floats2half2_rn(v.x, v.y);
        ((__half2*)xh)[2 * i + 1] = __floats2half2_rn(v.z, v.w);
    }
    long long base = (long long)b * C1;
    for (int j = t; j < C1; j += 256) {
        long long e = base + j;
        if (e < E) atomicAdd(&cnt[edge_at(ei, E + e, is64) >> 7], 1);
    }
    __syncthreads();
    for (int i = t; i < NB; i += 256) {
        int c = cnt[i];
        rbase[i] = c ? atomicAdd(&bcur[i], c) : 0;
        cnt[i] = 0;
    }
    __syncthreads();
    for (int j = t; j < C1; j += 256) {
        long long e = base + j;
        if (e < E) {
            int s = edge_at(ei, e, is64);
            int d = edge_at(ei, E + e, is64);
            int bu = d >> 7;
            unsigned rec = (unsigned)s | ((unsigned)(d & (W0 - 1)) << 20);
            int pos = rbase[bu] + atomicAdd(&cnt[bu], 1);
            if (pos < CAP) recs[(long long)bu * CAP + pos] = rec;
            else {
                int op = atomicAdd(ovf_cnt, 1);
                if (op < OVF_CAP) ovf[op] = ((unsigned long long)bu << 32) | rec;
            }
        }
    }
}

__global__ __launch_bounds__(512) void k_p2agg_g(
        const unsigned int* __restrict__ recs,
        const int* __restrict__ bcur, const int* __restrict__ ovf_cnt,
        const unsigned long long* __restrict__ ovf,
        const __half* __restrict__ xh, const __half* __restrict__ Bp,
        const float* __restrict__ bl, float* __restrict__ out, int N)
{
    __shared__ int cnt[W0];
    __shared__ int off[W0];
    __shared__ int sl[CAP];
    __shared__ __half aw[8][16][136];
    __shared__ int s_oc;
    int t = threadIdx.x, b = blockIdx.x;
    long long e0g = (long long)b * CAP;
    int ne = bcur[b];
    if (ne > CAP) ne = CAP;
    if (t == 0) s_oc = min(*ovf_cnt, OVF_CAP);

    if (t < W0) cnt[t] = 0;
    __syncthreads();
    for (int e = t; e < ne; e += 512)
        atomicAdd(&cnt[recs[e0g + e] >> 20], 1);
    __syncthreads();
    if (t < W0) off[t] = cnt[t];
    __syncthreads();
    for (int d = 1; d < W0; d <<= 1) {
        int v = 0;
        if (t < W0 && t >= d) v = off[t - d];
        __syncthreads();
        if (t < W0) off[t] += v;
        __syncthreads();
    }
    if (t < W0) cnt[t] = (t > 0) ? off[t - 1] : 0;
    __syncthreads();
    for (int e = t; e < ne; e += 512) {
        unsigned r = recs[e0g + e];
        int pos = atomicAdd(&cnt[r >> 20], 1);
        sl[pos] = (int)(r & 0xFFFFFu);
    }
    __syncthreads();

    int lane = t & 63;
    int wid  = t >> 6;
    int oc   = s_oc;
    const __half2* x2 = (const __half2*)xh;

    for (int i = 0; i < 16; ++i) {
        int n = wid * 16 + i;
        int node = b * W0 + n;
        if (node >= N) break;
        int s0 = (n > 0) ? off[n - 1] : 0;
        int s1 = off[n];
        float ax = 0.f, ay = 0.f;
        int e = s0;
        for (; e + 8 <= s1; e += 8) {
            int ss[8];
#pragma unroll
            for (int u = 0; u < 8; ++u) ss[u] = sl[e + u];
            __half2 h[8];
#pragma unroll
            for (int u = 0; u < 8; ++u) h[u] = x2[(long long)ss[u] * 64 + lane];
#pragma unroll
            for (int u = 0; u < 8; ++u) {
                float2 v = __half22float2(h[u]);
                ax += v.x; ay += v.y;
            }
        }
        for (; e + 2 <= s1; e += 2) {
            int sa = sl[e], sb = sl[e + 1];
            float2 v0 = __half22float2(x2[(long long)sa * 64 + lane]);
            float2 v1 = __half22float2(x2[(long long)sb * 64 + lane]);
            ax += v0.x + v1.x;
            ay += v0.y + v1.y;
        }
        if (e < s1) {
            float2 v = __half22float2(x2[(long long)sl[e] * 64 + lane]);
            ax += v.x; ay += v.y;
        }
        int extra = 0;
        for (int k = 0; k < oc; ++k) {
            unsigned long long v = ovf[k];
            if ((int)(v >> 32) == b) {
                unsigned rec = (unsigned)v;
                if ((int)(rec >> 20) == n) {
                    float2 w = __half22float2(x2[(long long)(rec & 0xFFFFFu) * 64 + lane]);
                    ax += w.x; ay += w.y; ++extra;
                }
            }
        }
        float inv = 1.0f / fmaxf((float)(s1 - s0 + extra), 1.0f);
        *(__half2*)&aw[wid][i][2 * lane] = __floats2half2_rn(ax * inv, ay * inv);
    }

    f32x4 acc[8];
#pragma unroll
    for (int c = 0; c < 8; ++c) acc[c] = (f32x4){0.f, 0.f, 0.f, 0.f};

    int rn = b * W0 + wid * 16 + (lane & 15);
    long long rx = (rn < N) ? rn : (N - 1);
    int koff = (lane >> 4) * 8;
#pragma unroll
    for (int s = 0; s < 8; ++s) {
        f16x8 a;
        if (s < 4) a = *(const f16x8*)&aw[wid][lane & 15][s * 32 + koff];
        else       a = *(const f16x8*)(xh + rx * 128 + (s & 3) * 32 + koff);
        const __half* bp = Bp + ((s * 8) * 64 + lane) * 8;
#pragma unroll
        for (int tt = 0; tt < 8; ++tt) {
            f16x8 bf = *(const f16x8*)(bp + tt * 512);
            acc[tt] = __builtin_amdgcn_mfma_f32_16x16x32_f16(a, bf, acc[tt], 0, 0, 0);
        }
    }

    float bias[8];
#pragma unroll
    for (int tt = 0; tt < 8; ++tt) bias[tt] = bl[tt * 16 + (lane & 15)];

#pragma unroll
    for (int r = 0; r < 4; ++r) {
        int node = b * W0 + wid * 16 + (lane >> 4) * 4 + r;
        float v[8];
        float ss = 0.f;
#pragma unroll
        for (int tt = 0; tt < 8; ++tt) {
            v[tt] = acc[tt][r] + bias[tt];
            ss = fmaf(v[tt], v[tt], ss);
        }
        ss += __shfl_xor(ss, 1, 64);
        ss += __shfl_xor(ss, 2, 64);
        ss += __shfl_xor(ss, 4, 64);
        ss += __shfl_xor(ss, 8, 64);
        float scale = 1.0f / fmaxf(sqrtf(ss), 1e-12f);
        if (node < N) {
            float* op = out + (long long)node * D + (lane & 15);
#pragma unroll
            for (int tt = 0; tt < 8; ++tt)
                op[tt * 16] = v[tt] * scale;
        }
    }
}

// ======================= FALLBACK PATH (proven, fp32) =======================
__global__ void k_detect(const int* __restrict__ ei, int* flag, long long E) {
    int l = threadIdx.x;
    int bad = 0;
    if (l < E)       bad |= (ei[2 * l + 1] != 0);
    if (l + 64 < E)  bad |= (ei[2 * (l + 64) + 1] != 0);
    unsigned long long m = __ballot(bad);
    if (l == 0) *flag = (m == 0ull) ? 1 : 0;
}

__global__ void k_transpose(const float* __restrict__ Wl, const float* __restrict__ Wr,
                            float* __restrict__ WtL, float* __restrict__ WtR) {
    int t = blockIdx.x * 256 + threadIdx.x;
    if (t < D * D) {
        int o = t >> 7, k = t & 127;
        WtL[k * D + o] = Wl[t];
        WtR[k * D + o] = Wr[t];
    }
}

__global__ __launch_bounds__(256) void k_p1count(const int* __restrict__ ei,
                                                 const int* __restrict__ flag,
                                                 int* __restrict__ bcount, long long E) {
    __shared__ int cnt[NB];
    for (int i = threadIdx.x; i < NB; i += 256) cnt[i] = 0;
    __syncthreads();
    int is64 = *flag;
    long long base = (long long)blockIdx.x * C1;
    for (int j = threadIdx.x; j < C1; j += 256) {
        long long e = base + j;
        if (e < E) atomicAdd(&cnt[edge_at(ei, E + e, is64) >> 7], 1);
    }
    __syncthreads();
    for (int i = threadIdx.x; i < NB; i += 256) {
        int c = cnt[i];
        if (c) atomicAdd(&bcount[i], c);
    }
}

__global__ __launch_bounds__(1024) void k_bscan(const int* __restrict__ bcount,
                                                int* __restrict__ bstart,
                                                int* __restrict__ bcur,
                                                int* __restrict__ offs) {
    __shared__ int sh[1024];
    int t = threadIdx.x;
    sh[t] = (t < NB) ? bcount[t] : 0;
    __syncthreads();
    for (int d = 1; d < 1024; d <<= 1) {
        int v = (t >= d) ? sh[t - d] : 0;
        __syncthreads();
        sh[t] += v;
        __syncthreads();
    }
    if (t < NB) {
        int ex = (t > 0) ? sh[t - 1] : 0;
        bstart[t] = ex;
        bcur[t] = ex;
    }
    if (t == NB - 1) {
        bstart[NB] = sh[NB - 1];
        offs[NN] = sh[NB - 1];
    }
}

__global__ __launch_bounds__(256) void k_p1scatter(const int* __restrict__ ei,
                                                   const int* __restrict__ flag,
                                                   int* __restrict__ bcur,
                                                   unsigned int* __restrict__ recs,
                                                   long long E) {
    __shared__ int cnt[NB];
    __shared__ int rbase[NB];
    for (int i = threadIdx.x; i < NB; i += 256) cnt[i] = 0;
    __syncthreads();
    int is64 = *flag;
    long long base = (long long)blockIdx.x * C1;
    for (int j = threadIdx.x; j < C1; j += 256) {
        long long e = base + j;
        if (e < E) atomicAdd(&cnt[edge_at(ei, E + e, is64) >> 7], 1);
    }
    __syncthreads();
    for (int i = threadIdx.x; i < NB; i += 256) {
        int c = cnt[i];
        rbase[i] = c ? atomicAdd(&bcur[i], c) : 0;
    }
    __syncthreads();
    for (int i = threadIdx.x; i < NB; i += 256) cnt[i] = 0;
    __syncthreads();
    for (int j = threadIdx.x; j < C1; j += 256) {
        long long e = base + j;
        if (e < E) {
            int s = edge_at(ei, e, is64);
            int d = edge_at(ei, E + e, is64);
            int bu = d >> 7;
            int pos = rbase[bu] + atomicAdd(&cnt[bu], 1);
            recs[pos] = (unsigned)s | ((unsigned)(d & (W0 - 1)) << 20);
        }
    }
}

__global__ __launch_bounds__(256) void k_p2(const unsigned int* __restrict__ recs,
                                            const int* __restrict__ bstart,
                                            int* __restrict__ offs,
                                            int* __restrict__ srcs, int N) {
    __shared__ int cnt[W0];
    __shared__ int off[W0];
    int t = threadIdx.x;
    int bu = blockIdx.x;
    int e0 = bstart[bu], e1 = bstart[bu + 1];
    if (t < W0) cnt[t] = 0;
    __syncthreads();
    for (int e = e0 + t; e < e1; e += 256)
        atomicAdd(&cnt[recs[e] >> 20], 1);
    __syncthreads();
    if (t < W0) off[t] = cnt[t];
    __syncthreads();
    for (int d = 1; d < W0; d <<= 1) {
        int v = 0;
        if (t < W0 && t >= d) v = off[t - d];
        __syncthreads();
        if (t < W0) off[t] += v;
        __syncthreads();
    }
    if (t < W0) {
        int ex = (t > 0) ? off[t - 1] : 0;
        int node = bu * W0 + t;
        if (node < N) offs[node] = e0 + ex;
        cnt[t] = e0 + ex;
    }
    __syncthreads();
    for (int e = e0 + t; e < e1; e += 256) {
        unsigned r = recs[e];
        int pos = atomicAdd(&cnt[r >> 20], 1);
        srcs[pos] = (int)(r & 0xFFFFFu);
    }
}

__global__ __launch_bounds__(256) void k_agg(const float* __restrict__ x,
                                             const int* __restrict__ offs,
                                             const int* __restrict__ srcs,
                                             float* agg, int N) {
    int lane = threadIdx.x & 63;
    int wid = __builtin_amdgcn_readfirstlane(threadIdx.x >> 6);
    int node = blockIdx.x * 4 + wid;
    if (node >= N) return;
    int e0 = offs[node], e1 = offs[node + 1];
    const float2* x2 = (const float2*)x;
    float ax = 0.f, ay = 0.f;
    int e = e0;
    for (; e + 4 <= e1; e += 4) {
        int s0 = srcs[e], s1 = srcs[e + 1], s2 = srcs[e + 2], s3 = srcs[e + 3];
        float2 v0 = x2[(long long)s0 * 64 + lane];
        float2 v1 = x2[(long long)s1 * 64 + lane];
        float2 v2 = x2[(long long)s2 * 64 + lane];
        float2 v3 = x2[(long long)s3 * 64 + lane];
        ax += v0.x + v1.x + v2.x + v3.x;
        ay += v0.y + v1.y + v2.y + v3.y;
    }
    for (; e < e1; ++e) {
        int s = srcs[e];
        float2 v = x2[(long long)s * 64 + lane];
        ax += v.x; ay += v.y;
    }
    float inv = 1.0f / fmaxf((float)(e1 - e0), 1.0f);
    float2 o; o.x = ax * inv; o.y = ay * inv;
    ((float2*)agg)[(long long)node * 64 + lane] = o;
}

__global__ __launch_bounds__(256) void k_scatterB(const float* __restrict__ x,
                                                  const int* __restrict__ ei,
                                                  const int* __restrict__ flag,
                                                  float* out, float* deg, long long E) {
    int lane = threadIdx.x & 63;
    long long e = (long long)blockIdx.x * 4 + (threadIdx.x >> 6);
    if (e >= E) return;
    int is64 = *flag;
    int s = edge_at(ei, e, is64);
    int d = edge_at(ei, E + e, is64);
    atomicAdd(&out[(long long)d * D + lane], x[(long long)s * D + lane]);
    atomicAdd(&out[(long long)d * D + 64 + lane], x[(long long)s * D + 64 + lane]);
    if (lane == 0) atomicAdd(&deg[d], 1.0f);
}

__global__ void k_meanB(float* out, const float* __restrict__ deg) {
    long long i = (long long)blockIdx.x * 256 + threadIdx.x;
    if (i >= (long long)NN * D) return;
    out[i] *= 1.0f / fmaxf(deg[i >> 7], 1.0f);
}

__global__ __launch_bounds__(256) void k_gemm(const float* __restrict__ x,
                                              const float* agg,
                                              const float* __restrict__ WtL,
                                              const float* __restrict__ WtR,
                                              const float* __restrict__ bl,
                                              float* out, int N) {
    __shared__ float Bs[64 * D];
    int t = threadIdx.x;
    int tx = t & 15;
    int ty = t >> 4;
    int row0 = blockIdx.x * 64 + ty * 4;
    int c0a = tx * 4;
    int c0b = 64 + tx * 4;

    float acc[4][8];
    float4 b0 = *(const float4*)(bl + c0a);
    float4 b1 = *(const float4*)(bl + c0b);
#pragma unroll
    for (int r = 0; r < 4; ++r) {
        acc[r][0] = b0.x; acc[r][1] = b0.y; acc[r][2] = b0.z; acc[r][3] = b0.w;
        acc[r][4] = b1.x; acc[r][5] = b1.y; acc[r][6] = b1.z; acc[r][7] = b1.w;
    }

    long long rws[4];
#pragma unroll
    for (int r = 0; r < 4; ++r) {
        int rr = row0 + r;
        rws[r] = (rr < N) ? (long long)rr : (long long)(N - 1);
    }

    for (int phase = 0; phase < 2; ++phase) {
        const float* A = phase ? x : agg;
        const float* W = phase ? WtR : WtL;
        const float4* Ar0 = (const float4*)(A + rws[0] * D);
        const float4* Ar1 = (const float4*)(A + rws[1] * D);
        const float4* Ar2 = (const float4*)(A + rws[2] * D);
        const float4* Ar3 = (const float4*)(A + rws[3] * D);

        for (int half = 0; half < 2; ++half) {
            if (phase | half) __syncthreads();
#pragma unroll
            for (int i = 0; i < 8; ++i) {
                int idx = t + i * 256;
                ((float4*)Bs)[idx] = ((const float4*)(W + half * 64 * D))[idx];
            }
            __syncthreads();

#pragma unroll 2
            for (int k4 = 0; k4 < 16; ++k4) {
                int ak4 = half * 16 + k4;
                float4 av[4];
                av[0] = Ar0[ak4]; av[1] = Ar1[ak4]; av[2] = Ar2[ak4]; av[3] = Ar3[ak4];
#pragma unroll
                for (int kk = 0; kk < 4; ++kk) {
                    int k = k4 * 4 + kk;
                    float4 w0 = *(const float4*)&Bs[k * D + c0a];
                    float4 w1 = *(const float4*)&Bs[k * D + c0b];
#pragma unroll
                    for (int r = 0; r < 4; ++r) {
                        float a = (kk == 0) ? av[r].x : (kk == 1) ? av[r].y
                                 : (kk == 2) ? av[r].z : av[r].w;
                        acc[r][0] = fmaf(a, w0.x, acc[r][0]);
                        acc[r][1] = fmaf(a, w0.y, acc[r][1]);
                        acc[r][2] = fmaf(a, w0.z, acc[r][2]);
                        acc[r][3] = fmaf(a, w0.w, acc[r][3]);
                        acc[r][4] = fmaf(a, w1.x, acc[r][4]);
                        acc[r][5] = fmaf(a, w1.y, acc[r][5]);
                        acc[r][6] = fmaf(a, w1.z, acc[r][6]);
                        acc[r][7] = fmaf(a, w1.w, acc[r][7]);
                    }
                }
            }
        }
    }

#pragma unroll
    for (int r = 0; r < 4; ++r) {
        float s = 0.f;
#pragma unroll
        for (int j = 0; j < 8; ++j) s = fmaf(acc[r][j], acc[r][j], s);
        s += __shfl_xor(s, 1, 64);
        s += __shfl_xor(s, 2, 64);
        s += __shfl_xor(s, 4, 64);
        s += __shfl_xor(s, 8, 64);
        float scale = 1.0f / fmaxf(sqrtf(s), 1e-12f);
        int rr = row0 + r;
        if (rr < N) {
            float4 v0, v1;
            v0.x = acc[r][0] * scale; v0.y = acc[r][1] * scale;
            v0.z = acc[r][2] * scale; v0.w = acc[r][3] * scale;
            v1.x = acc[r][4] * scale; v1.y = acc[r][5] * scale;
            v1.z = acc[r][6] * scale; v1.w = acc[r][7] * scale;
            float* op = out + (long long)rr * D;
            *(float4*)(op + c0a) = v0;
            *(float4*)(op + c0b) = v1;
        }
    }
}

extern "C" void kernel_launch(void* const* d_in, const int* in_sizes, int n_in,
                              void* d_out, int out_size, void* d_ws, size_t ws_size,
                              hipStream_t stream) {
    const float* x  = (const float*)d_in[0];
    const int*   ei = (const int*)d_in[1];
    const float* Wl = (const float*)d_in[2];
    const float* bl = (const float*)d_in[3];
    const float* Wr = (const float*)d_in[4];
    float* out = (float*)d_out;
    const long long E = (long long)in_sizes[1] / 2;

    char* ws = (char*)d_ws;
    int*      flag   = (int*)(ws + O_FLAG);
    int*      bcount = (int*)(ws + O_BCNT);
    int*      bstart = (int*)(ws + O_BSTART);
    int*      bcur   = (int*)(ws + O_BCUR);
    int*      ovfcM  = (int*)(ws + O_BCUR + 3200);   // middle-tier ovf counter
    float*    WtL    = (float*)(ws + O_WTL);
    float*    WtR    = (float*)(ws + O_WTR);
    __half*   Bph    = (__half*)(ws + O_WTL);
    int*      offs   = (int*)(ws + O_OFFS);          // fallback offs / fast-tier ncur
    float*    deg    = (float*)(ws + O_DEG);
    unsigned* recs   = (unsigned*)(ws + O_RECS);
    int*      srcs   = (int*)(ws + O_RECS + (size_t)E * 4);   // fallback only

    int pb = (int)((E + C1 - 1) / C1);

    // ---- fast tier: per-node slots, no sort ----
    {
        int*  ncur = (int*)(ws + O_OFFS);
        int*  ovfc = ncur + NN;                       // inside the (NN+64)-int region
        int*  nrec = (int*)(ws + O_RECS);
        const size_t O_OVF_N = O_RECS + (size_t)NN * NCAP * 4;
        unsigned long long* ovfN = (unsigned long long*)(ws + O_OVF_N);
        const size_t O_XH_N = O_OVF_N + (size_t)OVF_CAP * 8;
        __half* xh = (__half*)(ws + O_XH_N);
        size_t need = O_XH_N + (size_t)NN * D * 2;
        if (ws_size >= need) {
            hipMemsetAsync(ncur, 0, (size_t)(NN + 64) * 4, stream);
            k_build2<<<pb, 256, 0, stream>>>(x, ei, Wl, Wr, xh, Bph,
                                             ncur, ovfc, ovfN, nrec, E);
            k_aggemm<<<(NN + 63) / 64, 256, 0, stream>>>(nrec, ncur, ovfc, ovfN,
                                                         xh, Bph, bl, out, NN);
            return;
        }
    }

    // ---- middle tier: R6-proven bucket path ----
    {
        const size_t O_OVF = O_RECS + (size_t)NB * CAP * 4;
        unsigned long long* ovf = (unsigned long long*)(ws + O_OVF);
        const size_t O_XH = O_OVF + (size_t)OVF_CAP * 8;
        __half* xh = (__half*)(ws + O_XH);
        size_t need = O_XH + (size_t)NN * D * 2;
        if (ws_size >= need && E <= (long long)NB * CAP) {
            hipMemsetAsync(ws + O_BCUR, 0, 4096, stream);
            k_build<<<pb, 256, 0, stream>>>(x, ei, Wl, Wr, xh, Bph,
                                            bcur, ovfcM, ovf, recs, E);
            k_p2agg_g<<<NB, 512, 0, stream>>>(recs, bcur, ovfcM, ovf,
                                              xh, Bph, bl, out, NN);
            return;
        }
    }

    // -------- fallback: fp32 pipeline --------
    bool planA = ws_size >= O_RECS + (size_t)E * 8;
    k_detect<<<1, 64, 0, stream>>>(ei, flag, E);
    k_transpose<<<(D * D + 255) / 256, 256, 0, stream>>>(Wl, Wr, WtL, WtR);

    if (planA) {
        hipMemsetAsync(ws + O_BCNT, 0, (size_t)NB * 4, stream);
        k_p1count<<<pb, 256, 0, stream>>>(ei, flag, bcount, E);
        k_bscan<<<1, 1024, 0, stream>>>(bcount, bstart, bcur, offs);
        k_p1scatter<<<pb, 256, 0, stream>>>(ei, flag, bcur, recs, E);
        k_p2<<<NB, 256, 0, stream>>>(recs, bstart, offs, srcs, NN);
        k_agg<<<(NN + 3) / 4, 256, 0, stream>>>(x, offs, srcs, out, NN);
    } else {
        hipMemsetAsync(out, 0, (size_t)NN * D * 4, stream);
        hipMemsetAsync(ws + O_DEG, 0, (size_t)NN * 4, stream);
        k_scatterB<<<(int)((E + 3) / 4), 256, 0, stream>>>(x, ei, flag, out, deg, E);
        k_meanB<<<(int)(((long long)NN * D + 255) / 256), 256, 0, stream>>>(out, deg);
    }
    k_gemm<<<(NN + 63) / 64, 256, 0, stream>>>(x, out, WtL, WtR, bl, out, NN);
}

// Round 8
// 220.568 us; speedup vs baseline: 1.6031x; 1.6031x over previous
//
#include <hip/hip_runtime.h>
#include <hip/hip_fp16.h>
#include <stdint.h>

#define NN 100000
#define D 128
#define W0 128                         // nodes per bucket (power of 2)
#define NB ((NN + W0 - 1) / W0)        // 782 buckets
#define C1 4096                        // edges per chunk (391 partition blocks)
#define CAP 4096                       // per-bucket record capacity (mean 2046, +45 sigma)
#define OVF_CAP 65536                  // global overflow entries (degenerate inputs)

typedef _Float16 f16x8 __attribute__((ext_vector_type(8)));
typedef float f32x4 __attribute__((ext_vector_type(4)));

// ---- workspace layout (bytes) ----
static const size_t O_FLAG   = 0;                      // detect flag (fallback)
static const size_t O_BCNT   = 256;                    // NB ints (fallback)
static const size_t O_BSTART = O_BCNT + 4096;          // NB+1 ints (fallback)
static const size_t O_BCUR   = O_BSTART + 4096;        // NB ints + ovf counter @ +3200
static const size_t O_WTL    = O_BCUR + 4096;          // 64KB: packed Bp / WtL (fallback)
static const size_t O_WTR    = O_WTL + (size_t)D * D * 4;
static const size_t O_OFFS   = O_WTR + (size_t)D * D * 4;    // NN+1 ints (fallback)
static const size_t O_DEG    = O_OFFS + (size_t)(NN + 64) * 4;  // Plan B only
static const size_t O_RECS   = O_DEG + (size_t)NN * 4;       // NB*CAP recs (fast) / E recs (fallback)
static const size_t O_OVF    = O_RECS + (size_t)NB * CAP * 4;
static const size_t O_XH     = O_OVF + (size_t)OVF_CAP * 8;
static const size_t O_AGGH   = O_XH + (size_t)NN * D * 2;

__device__ __forceinline__ int edge_at(const int* ei, long long pos, int is64) {
    return is64 ? ei[2 * pos] : ei[pos];
}

__device__ __forceinline__ void detect_is64(const int* __restrict__ ei, long long E,
                                            int t, int* s_is64) {
    if (t < 64) {
        int bad = 0;
        if (t < E)      bad |= (ei[2 * t + 1] != 0);
        if (t + 64 < E) bad |= (ei[2 * (t + 64) + 1] != 0);
        unsigned long long m = __ballot(bad);
        if (t == 0) *s_is64 = (m == 0ull) ? 1 : 0;
    }
}

// ================= 4-DISPATCH FAST PATH =================
// K1: detect + weight-pack + fp16 conv + bucket append (CAP-strided regions).
// Edges cached in LDS during the histogram pass -> append pass reads LDS, not HBM.
__global__ __launch_bounds__(256) void k_build(
        const float* __restrict__ x, const int* __restrict__ ei,
        const float* __restrict__ Wl, const float* __restrict__ Wr,
        __half* __restrict__ xh, __half* __restrict__ Bp,
        int* __restrict__ bcur, int* __restrict__ ovf_cnt,
        unsigned long long* __restrict__ ovf,
        unsigned int* __restrict__ recs, long long E)
{
    __shared__ int2 ed[C1];            // 32 KB edge cache (src,dst)
    __shared__ int cnt[NB];
    __shared__ int rbase[NB];
    __shared__ int s_is64;
    int t = threadIdx.x, b = blockIdx.x;
    detect_is64(ei, E, t, &s_is64);
    for (int i = t; i < NB; i += 256) cnt[i] = 0;
    __syncthreads();
    int is64 = s_is64;

    // weight pack into MFMA B-fragment order (blocks 0..127)
    int idx = b * 256 + t;
    if (idx < 32768) {
        int j  = idx & 7;
        int l  = (idx >> 3) & 63;
        int tt = (idx >> 9) & 7;
        int s  = idx >> 12;
        int col = tt * 16 + (l & 15);
        int k   = s * 32 + (l >> 4) * 8 + j;
        float v = (k < 128) ? Wl[col * 128 + k] : Wr[col * 128 + (k - 128)];
        Bp[idx] = __float2half_rn(v);
    }
    // fp16 conversion of x (grid-stride)
    const long long n4 = (long long)NN * D / 4;
    for (long long i = (long long)b * 256 + t; i < n4; i += (long long)gridDim.x * 256) {
        float4 v = ((const float4*)x)[i];
        ((__half2*)xh)[2 * i]     = __floats2half2_rn(v.x, v.y);
        ((__half2*)xh)[2 * i + 1] = __floats2half2_rn(v.z, v.w);
    }
    // pass 1: load edges once (global) + LDS histogram
    long long base = (long long)b * C1;
    int m = (int)(((base + C1) <= E) ? C1 : (E > base ? E - base : 0));
    for (int j = t; j < m; j += 256) {
        long long e = base + j;
        int s = edge_at(ei, e, is64);
        int d = edge_at(ei, E + e, is64);
        ed[j] = make_int2(s, d);
        atomicAdd(&cnt[d >> 7], 1);
    }
    __syncthreads();
    // reserve per-bucket ranges
    for (int i = t; i < NB; i += 256) {
        int c = cnt[i];
        rbase[i] = c ? atomicAdd(&bcur[i], c) : 0;
        cnt[i] = 0;
    }
    __syncthreads();
    // pass 2: append from LDS cache
    for (int j = t; j < m; j += 256) {
        int s = ed[j].x, d = ed[j].y;
        int bu = d >> 7;
        unsigned rec = (unsigned)s | ((unsigned)(d & (W0 - 1)) << 20);
        int pos = rbase[bu] + atomicAdd(&cnt[bu], 1);
        if (pos < CAP) recs[(long long)bu * CAP + pos] = rec;
        else {
            int op = atomicAdd(ovf_cnt, 1);
            if (op < OVF_CAP) ovf[op] = ((unsigned long long)bu << 32) | rec;
        }
    }
}

// K2: per-bucket sort (LDS) + mean-aggregate gather -> fp16 aggh. No GEMM here:
// fusing the GEMM forces per-wave global B reads (R6: +30us) or kills occupancy.
__global__ __launch_bounds__(512) void k_p2agg(
        const unsigned int* __restrict__ recs,
        const int* __restrict__ bcur, const int* __restrict__ ovf_cnt,
        const unsigned long long* __restrict__ ovf,
        const __half* __restrict__ xh, __half* __restrict__ aggh, int N)
{
    __shared__ int cnt[W0];
    __shared__ int off[W0];
    __shared__ int sl[CAP];            // 16 KB; ne <= CAP guaranteed (excess -> ovf)
    __shared__ int s_oc;
    int t = threadIdx.x, b = blockIdx.x;
    long long e0g = (long long)b * CAP;
    int ne = bcur[b];
    if (ne > CAP) ne = CAP;
    if (t == 0) s_oc = min(*ovf_cnt, OVF_CAP);

    if (t < W0) cnt[t] = 0;
    __syncthreads();
    for (int e = t; e < ne; e += 512)
        atomicAdd(&cnt[recs[e0g + e] >> 20], 1);
    __syncthreads();
    if (t < W0) off[t] = cnt[t];
    __syncthreads();
    for (int d = 1; d < W0; d <<= 1) {
        int v = 0;
        if (t < W0 && t >= d) v = off[t - d];
        __syncthreads();
        if (t < W0) off[t] += v;
        __syncthreads();
    }
    if (t < W0) cnt[t] = (t > 0) ? off[t - 1] : 0;   // exclusive start = cursor
    __syncthreads();
    for (int e = t; e < ne; e += 512) {
        unsigned r = recs[e0g + e];
        int pos = atomicAdd(&cnt[r >> 20], 1);
        sl[pos] = (int)(r & 0xFFFFFu);
    }
    __syncthreads();

    int lane = t & 63;
    int wid  = t >> 6;
    int oc   = s_oc;
    const __half2* x2 = (const __half2*)xh;

    // gather: 16 nodes per wave, 8-deep MLP, half2/lane (full 256B row per edge)
    for (int i = 0; i < 16; ++i) {
        int n = wid * 16 + i;
        int node = b * W0 + n;
        if (node >= N) break;
        int s0 = (n > 0) ? off[n - 1] : 0;
        int s1 = off[n];
        float ax = 0.f, ay = 0.f;
        int e = s0;
        for (; e + 8 <= s1; e += 8) {
            int ss[8];
#pragma unroll
            for (int u = 0; u < 8; ++u) ss[u] = sl[e + u];
            __half2 h[8];
#pragma unroll
            for (int u = 0; u < 8; ++u) h[u] = x2[(long long)ss[u] * 64 + lane];
#pragma unroll
            for (int u = 0; u < 8; ++u) {
                float2 v = __half22float2(h[u]);
                ax += v.x; ay += v.y;
            }
        }
        for (; e + 2 <= s1; e += 2) {
            int sa = sl[e], sb = sl[e + 1];
            float2 v0 = __half22float2(x2[(long long)sa * 64 + lane]);
            float2 v1 = __half22float2(x2[(long long)sb * 64 + lane]);
            ax += v0.x + v1.x;
            ay += v0.y + v1.y;
        }
        if (e < s1) {
            float2 v = __half22float2(x2[(long long)sl[e] * 64 + lane]);
            ax += v.x; ay += v.y;
        }
        int extra = 0;
        for (int k = 0; k < oc; ++k) {          // overflow slow path (oc==0 normally)
            unsigned long long v = ovf[k];
            if ((int)(v >> 32) == b) {
                unsigned rec = (unsigned)v;
                if ((int)(rec >> 20) == n) {
                    float2 w = __half22float2(x2[(long long)(rec & 0xFFFFFu) * 64 + lane]);
                    ax += w.x; ay += w.y; ++extra;
                }
            }
        }
        float inv = 1.0f / fmaxf((float)(s1 - s0 + extra), 1.0f);
        ((__half2*)aggh)[(long long)node * 64 + lane] =
            __floats2half2_rn(ax * inv, ay * inv);
    }
}

// K3: MFMA GEMM out = [aggh | xh](N x 256) @ Bp(256 x 128) + b, row L2-norm.
// B staged ONCE per block in 64 KB LDS (proven 25us).
__global__ __launch_bounds__(256) void k_gemm_m(const __half* __restrict__ aggh,
                                                const __half* __restrict__ xh,
                                                const __half* __restrict__ Bp,
                                                const float* __restrict__ bl,
                                                float* __restrict__ out, int N) {
    __shared__ __half Bs[32768];   // 64 KB
    int t = threadIdx.x;
#pragma unroll
    for (int i = 0; i < 16; ++i) {
        int idx = t + i * 256;
        ((float4*)Bs)[idx] = ((const float4*)Bp)[idx];
    }
    int lane = t & 63;
    int wid  = t >> 6;
    int row0 = blockIdx.x * 128 + wid * 32;
    int rA = row0 + (lane & 15);
    int rB = rA + 16;
    long long ra = (rA < N) ? rA : (N - 1);
    long long rb = (rB < N) ? rB : (N - 1);
    int koff = (lane >> 4) * 8;

    f32x4 acc[2][8];
#pragma unroll
    for (int r = 0; r < 2; ++r)
#pragma unroll
        for (int c = 0; c < 8; ++c)
            acc[r][c] = (f32x4){0.f, 0.f, 0.f, 0.f};

    __syncthreads();

#pragma unroll
    for (int s = 0; s < 8; ++s) {
        const __half* Ap = (s < 4) ? aggh : xh;
        int kb = (s & 3) * 32 + koff;
        f16x8 a0 = *(const f16x8*)(Ap + ra * 128 + kb);
        f16x8 a1 = *(const f16x8*)(Ap + rb * 128 + kb);
        const __half* bs = Bs + s * 4096 + lane * 8;
#pragma unroll
        for (int tt = 0; tt < 8; ++tt) {
            f16x8 bf = *(const f16x8*)(bs + tt * 512);
            acc[0][tt] = __builtin_amdgcn_mfma_f32_16x16x32_f16(a0, bf, acc[0][tt], 0, 0, 0);
            acc[1][tt] = __builtin_amdgcn_mfma_f32_16x16x32_f16(a1, bf, acc[1][tt], 0, 0, 0);
        }
    }

    float bias[8];
#pragma unroll
    for (int tt = 0; tt < 8; ++tt) bias[tt] = bl[tt * 16 + (lane & 15)];

#pragma unroll
    for (int rt = 0; rt < 2; ++rt) {
#pragma unroll
        for (int r = 0; r < 4; ++r) {
            int row = row0 + rt * 16 + (lane >> 4) * 4 + r;
            float v[8];
            float ss = 0.f;
#pragma unroll
            for (int tt = 0; tt < 8; ++tt) {
                v[tt] = acc[rt][tt][r] + bias[tt];
                ss = fmaf(v[tt], v[tt], ss);
            }
            ss += __shfl_xor(ss, 1, 64);
            ss += __shfl_xor(ss, 2, 64);
            ss += __shfl_xor(ss, 4, 64);
            ss += __shfl_xor(ss, 8, 64);
            float scale = 1.0f / fmaxf(sqrtf(ss), 1e-12f);
            if (row < N) {
                float* op = out + (long long)row * D + (lane & 15);
#pragma unroll
                for (int tt = 0; tt < 8; ++tt)
                    op[tt * 16] = v[tt] * scale;
            }
        }
    }
}

// ======================= FALLBACK PATH (proven, fp32) =======================
__global__ void k_detect(const int* __restrict__ ei, int* flag, long long E) {
    int l = threadIdx.x;
    int bad = 0;
    if (l < E)       bad |= (ei[2 * l + 1] != 0);
    if (l + 64 < E)  bad |= (ei[2 * (l + 64) + 1] != 0);
    unsigned long long m = __ballot(bad);
    if (l == 0) *flag = (m == 0ull) ? 1 : 0;
}

__global__ void k_transpose(const float* __restrict__ Wl, const float* __restrict__ Wr,
                            float* __restrict__ WtL, float* __restrict__ WtR) {
    int t = blockIdx.x * 256 + threadIdx.x;
    if (t < D * D) {
        int o = t >> 7, k = t & 127;
        WtL[k * D + o] = Wl[t];
        WtR[k * D + o] = Wr[t];
    }
}

__global__ __launch_bounds__(256) void k_p1count(const int* __restrict__ ei,
                                                 const int* __restrict__ flag,
                                                 int* __restrict__ bcount, long long E) {
    __shared__ int cnt[NB];
    for (int i = threadIdx.x; i < NB; i += 256) cnt[i] = 0;
    __syncthreads();
    int is64 = *flag;
    long long base = (long long)blockIdx.x * C1;
    for (int j = threadIdx.x; j < C1; j += 256) {
        long long e = base + j;
        if (e < E) atomicAdd(&cnt[edge_at(ei, E + e, is64) >> 7], 1);
    }
    __syncthreads();
    for (int i = threadIdx.x; i < NB; i += 256) {
        int c = cnt[i];
        if (c) atomicAdd(&bcount[i], c);
    }
}

__global__ __launch_bounds__(1024) void k_bscan(const int* __restrict__ bcount,
                                                int* __restrict__ bstart,
                                                int* __restrict__ bcur,
                                                int* __restrict__ offs) {
    __shared__ int sh[1024];
    int t = threadIdx.x;
    sh[t] = (t < NB) ? bcount[t] : 0;
    __syncthreads();
    for (int d = 1; d < 1024; d <<= 1) {
        int v = (t >= d) ? sh[t - d] : 0;
        __syncthreads();
        sh[t] += v;
        __syncthreads();
    }
    if (t < NB) {
        int ex = (t > 0) ? sh[t - 1] : 0;
        bstart[t] = ex;
        bcur[t] = ex;
    }
    if (t == NB - 1) {
        bstart[NB] = sh[NB - 1];
        offs[NN] = sh[NB - 1];
    }
}

__global__ __launch_bounds__(256) void k_p1scatter(const int* __restrict__ ei,
                                                   const int* __restrict__ flag,
                                                   int* __restrict__ bcur,
                                                   unsigned int* __restrict__ recs,
                                                   long long E) {
    __shared__ int cnt[NB];
    __shared__ int rbase[NB];
    for (int i = threadIdx.x; i < NB; i += 256) cnt[i] = 0;
    __syncthreads();
    int is64 = *flag;
    long long base = (long long)blockIdx.x * C1;
    for (int j = threadIdx.x; j < C1; j += 256) {
        long long e = base + j;
        if (e < E) atomicAdd(&cnt[edge_at(ei, E + e, is64) >> 7], 1);
    }
    __syncthreads();
    for (int i = threadIdx.x; i < NB; i += 256) {
        int c = cnt[i];
        rbase[i] = c ? atomicAdd(&bcur[i], c) : 0;
    }
    __syncthreads();
    for (int i = threadIdx.x; i < NB; i += 256) cnt[i] = 0;
    __syncthreads();
    for (int j = threadIdx.x; j < C1; j += 256) {
        long long e = base + j;
        if (e < E) {
            int s = edge_at(ei, e, is64);
            int d = edge_at(ei, E + e, is64);
            int bu = d >> 7;
            int pos = rbase[bu] + atomicAdd(&cnt[bu], 1);
            recs[pos] = (unsigned)s | ((unsigned)(d & (W0 - 1)) << 20);
        }
    }
}

__global__ __launch_bounds__(256) void k_p2(const unsigned int* __restrict__ recs,
                                            const int* __restrict__ bstart,
                                            int* __restrict__ offs,
                                            int* __restrict__ srcs, int N) {
    __shared__ int cnt[W0];
    __shared__ int off[W0];
    int t = threadIdx.x;
    int bu = blockIdx.x;
    int e0 = bstart[bu], e1 = bstart[bu + 1];
    if (t < W0) cnt[t] = 0;
    __syncthreads();
    for (int e = e0 + t; e < e1; e += 256)
        atomicAdd(&cnt[recs[e] >> 20], 1);
    __syncthreads();
    if (t < W0) off[t] = cnt[t];
    __syncthreads();
    for (int d = 1; d < W0; d <<= 1) {
        int v = 0;
        if (t < W0 && t >= d) v = off[t - d];
        __syncthreads();
        if (t < W0) off[t] += v;
        __syncthreads();
    }
    if (t < W0) {
        int ex = (t > 0) ? off[t - 1] : 0;
        int node = bu * W0 + t;
        if (node < N) offs[node] = e0 + ex;
        cnt[t] = e0 + ex;
    }
    __syncthreads();
    for (int e = e0 + t; e < e1; e += 256) {
        unsigned r = recs[e];
        int pos = atomicAdd(&cnt[r >> 20], 1);
        srcs[pos] = (int)(r & 0xFFFFFu);
    }
}

__global__ __launch_bounds__(256) void k_agg(const float* __restrict__ x,
                                             const int* __restrict__ offs,
                                             const int* __restrict__ srcs,
                                             float* agg, int N) {
    int lane = threadIdx.x & 63;
    int wid = __builtin_amdgcn_readfirstlane(threadIdx.x >> 6);
    int node = blockIdx.x * 4 + wid;
    if (node >= N) return;
    int e0 = offs[node], e1 = offs[node + 1];
    const float2* x2 = (const float2*)x;
    float ax = 0.f, ay = 0.f;
    int e = e0;
    for (; e + 4 <= e1; e += 4) {
        int s0 = srcs[e], s1 = srcs[e + 1], s2 = srcs[e + 2], s3 = srcs[e + 3];
        float2 v0 = x2[(long long)s0 * 64 + lane];
        float2 v1 = x2[(long long)s1 * 64 + lane];
        float2 v2 = x2[(long long)s2 * 64 + lane];
        float2 v3 = x2[(long long)s3 * 64 + lane];
        ax += v0.x + v1.x + v2.x + v3.x;
        ay += v0.y + v1.y + v2.y + v3.y;
    }
    for (; e < e1; ++e) {
        int s = srcs[e];
        float2 v = x2[(long long)s * 64 + lane];
        ax += v.x; ay += v.y;
    }
    float inv = 1.0f / fmaxf((float)(e1 - e0), 1.0f);
    float2 o; o.x = ax * inv; o.y = ay * inv;
    ((float2*)agg)[(long long)node * 64 + lane] = o;
}

__global__ __launch_bounds__(256) void k_scatterB(const float* __restrict__ x,
                                                  const int* __restrict__ ei,
                                                  const int* __restrict__ flag,
                                                  float* out, float* deg, long long E) {
    int lane = threadIdx.x & 63;
    long long e = (long long)blockIdx.x * 4 + (threadIdx.x >> 6);
    if (e >= E) return;
    int is64 = *flag;
    int s = edge_at(ei, e, is64);
    int d = edge_at(ei, E + e, is64);
    atomicAdd(&out[(long long)d * D + lane], x[(long long)s * D + lane]);
    atomicAdd(&out[(long long)d * D + 64 + lane], x[(long long)s * D + 64 + lane]);
    if (lane == 0) atomicAdd(&deg[d], 1.0f);
}

__global__ void k_meanB(float* out, const float* __restrict__ deg) {
    long long i = (long long)blockIdx.x * 256 + threadIdx.x;
    if (i >= (long long)NN * D) return;
    out[i] *= 1.0f / fmaxf(deg[i >> 7], 1.0f);
}

__global__ __launch_bounds__(256) void k_gemm(const float* __restrict__ x,
                                              const float* agg,
                                              const float* __restrict__ WtL,
                                              const float* __restrict__ WtR,
                                              const float* __restrict__ bl,
                                              float* out, int N) {
    __shared__ float Bs[64 * D];
    int t = threadIdx.x;
    int tx = t & 15;
    int ty = t >> 4;
    int row0 = blockIdx.x * 64 + ty * 4;
    int c0a = tx * 4;
    int c0b = 64 + tx * 4;

    float acc[4][8];
    float4 b0 = *(const float4*)(bl + c0a);
    float4 b1 = *(const float4*)(bl + c0b);
#pragma unroll
    for (int r = 0; r < 4; ++r) {
        acc[r][0] = b0.x; acc[r][1] = b0.y; acc[r][2] = b0.z; acc[r][3] = b0.w;
        acc[r][4] = b1.x; acc[r][5] = b1.y; acc[r][6] = b1.z; acc[r][7] = b1.w;
    }

    long long rws[4];
#pragma unroll
    for (int r = 0; r < 4; ++r) {
        int rr = row0 + r;
        rws[r] = (rr < N) ? (long long)rr : (long long)(N - 1);
    }

    for (int phase = 0; phase < 2; ++phase) {
        const float* A = phase ? x : agg;
        const float* W = phase ? WtR : WtL;
        const float4* Ar0 = (const float4*)(A + rws[0] * D);
        const float4* Ar1 = (const float4*)(A + rws[1] * D);
        const float4* Ar2 = (const float4*)(A + rws[2] * D);
        const float4* Ar3 = (const float4*)(A + rws[3] * D);

        for (int half = 0; half < 2; ++half) {
            if (phase | half) __syncthreads();
#pragma unroll
            for (int i = 0; i < 8; ++i) {
                int idx = t + i * 256;
                ((float4*)Bs)[idx] = ((const float4*)(W + half * 64 * D))[idx];
            }
            __syncthreads();

#pragma unroll 2
            for (int k4 = 0; k4 < 16; ++k4) {
                int ak4 = half * 16 + k4;
                float4 av[4];
                av[0] = Ar0[ak4]; av[1] = Ar1[ak4]; av[2] = Ar2[ak4]; av[3] = Ar3[ak4];
#pragma unroll
                for (int kk = 0; kk < 4; ++kk) {
                    int k = k4 * 4 + kk;
                    float4 w0 = *(const float4*)&Bs[k * D + c0a];
                    float4 w1 = *(const float4*)&Bs[k * D + c0b];
#pragma unroll
                    for (int r = 0; r < 4; ++r) {
                        float a = (kk == 0) ? av[r].x : (kk == 1) ? av[r].y
                                 : (kk == 2) ? av[r].z : av[r].w;
                        acc[r][0] = fmaf(a, w0.x, acc[r][0]);
                        acc[r][1] = fmaf(a, w0.y, acc[r][1]);
                        acc[r][2] = fmaf(a, w0.z, acc[r][2]);
                        acc[r][3] = fmaf(a, w0.w, acc[r][3]);
                        acc[r][4] = fmaf(a, w1.x, acc[r][4]);
                        acc[r][5] = fmaf(a, w1.y, acc[r][5]);
                        acc[r][6] = fmaf(a, w1.z, acc[r][6]);
                        acc[r][7] = fmaf(a, w1.w, acc[r][7]);
                    }
                }
            }
        }
    }

#pragma unroll
    for (int r = 0; r < 4; ++r) {
        float s = 0.f;
#pragma unroll
        for (int j = 0; j < 8; ++j) s = fmaf(acc[r][j], acc[r][j], s);
        s += __shfl_xor(s, 1, 64);
        s += __shfl_xor(s, 2, 64);
        s += __shfl_xor(s, 4, 64);
        s += __shfl_xor(s, 8, 64);
        float scale = 1.0f / fmaxf(sqrtf(s), 1e-12f);
        int rr = row0 + r;
        if (rr < N) {
            float4 v0, v1;
            v0.x = acc[r][0] * scale; v0.y = acc[r][1] * scale;
            v0.z = acc[r][2] * scale; v0.w = acc[r][3] * scale;
            v1.x = acc[r][4] * scale; v1.y = acc[r][5] * scale;
            v1.z = acc[r][6] * scale; v1.w = acc[r][7] * scale;
            float* op = out + (long long)rr * D;
            *(float4*)(op + c0a) = v0;
            *(float4*)(op + c0b) = v1;
        }
    }
}

extern "C" void kernel_launch(void* const* d_in, const int* in_sizes, int n_in,
                              void* d_out, int out_size, void* d_ws, size_t ws_size,
                              hipStream_t stream) {
    const float* x  = (const float*)d_in[0];
    const int*   ei = (const int*)d_in[1];
    const float* Wl = (const float*)d_in[2];
    const float* bl = (const float*)d_in[3];
    const float* Wr = (const float*)d_in[4];
    float* out = (float*)d_out;
    const long long E = (long long)in_sizes[1] / 2;

    char* ws = (char*)d_ws;
    int*      flag   = (int*)(ws + O_FLAG);
    int*      bcount = (int*)(ws + O_BCNT);
    int*      bstart = (int*)(ws + O_BSTART);
    int*      bcur   = (int*)(ws + O_BCUR);
    int*      ovfc   = (int*)(ws + O_BCUR + 3200);
    float*    WtL    = (float*)(ws + O_WTL);
    float*    WtR    = (float*)(ws + O_WTR);
    __half*   Bph    = (__half*)(ws + O_WTL);     // 64 KB, reuses WtL slot (fast path)
    int*      offs   = (int*)(ws + O_OFFS);
    float*    deg    = (float*)(ws + O_DEG);
    unsigned* recs   = (unsigned*)(ws + O_RECS);
    int*      srcs   = (int*)(ws + O_RECS + (size_t)E * 4);   // fallback only
    unsigned long long* ovf = (unsigned long long*)(ws + O_OVF);
    __half*   xh     = (__half*)(ws + O_XH);
    __half*   aggh   = (__half*)(ws + O_AGGH);

    int pb = (int)((E + C1 - 1) / C1);
    size_t fast_bytes = O_AGGH + (size_t)NN * D * 2;
    bool useF = (ws_size >= fast_bytes) && (E <= (long long)NB * CAP);

    if (useF) {
        // 4-dispatch pipeline: zero cursors -> build -> sort+gather -> MFMA GEMM.
        hipMemsetAsync(ws + O_BCUR, 0, 4096, stream);
        k_build<<<pb, 256, 0, stream>>>(x, ei, Wl, Wr, xh, Bph, bcur, ovfc, ovf, recs, E);
        k_p2agg<<<NB, 512, 0, stream>>>(recs, bcur, ovfc, ovf, xh, aggh, NN);
        k_gemm_m<<<(NN + 127) / 128, 256, 0, stream>>>(aggh, xh, Bph, bl, out, NN);
        return;
    }

    // -------- fallback: fp32 pipeline --------
    bool planA = ws_size >= O_RECS + (size_t)E * 8;
    k_detect<<<1, 64, 0, stream>>>(ei, flag, E);
    k_transpose<<<(D * D + 255) / 256, 256, 0, stream>>>(Wl, Wr, WtL, WtR);

    if (planA) {
        hipMemsetAsync(ws + O_BCNT, 0, (size_t)NB * 4, stream);
        k_p1count<<<pb, 256, 0, stream>>>(ei, flag, bcount, E);
        k_bscan<<<1, 1024, 0, stream>>>(bcount, bstart, bcur, offs);
        k_p1scatter<<<pb, 256, 0, stream>>>(ei, flag, bcur, recs, E);
        k_p2<<<NB, 256, 0, stream>>>(recs, bstart, offs, srcs, NN);
        k_agg<<<(NN + 3) / 4, 256, 0, stream>>>(x, offs, srcs, out, NN);
    } else {
        hipMemsetAsync(out, 0, (size_t)NN * D * 4, stream);
        hipMemsetAsync(ws + O_DEG, 0, (size_t)NN * 4, stream);
        k_scatterB<<<(int)((E + 3) / 4), 256, 0, stream>>>(x, ei, flag, out, deg, E);
        k_meanB<<<(int)(((long long)NN * D + 255) / 256), 256, 0, stream>>>(out, deg);
    }
    k_gemm<<<(NN + 63) / 64, 256, 0, stream>>>(x, out, WtL, WtR, bl, out, NN);
}